// Round 8
// baseline (134.596 us; speedup 1.0000x reference)
//
#include <hip/hip_runtime.h>

#define NN 8192
#define FF 256
#define MM 128
#define HSLOTS 262144   // power of 2, 2x edge count

typedef __attribute__((ext_vector_type(8))) short bf16x8;
typedef __attribute__((ext_vector_type(4))) float f32x4;

// ws layout (bytes):
// [0, 16K): partial sums, 3 arrays x 64 slots, 64B apart
// [16K, +2MB): zb bf16 [NN][MM]  (row-major, for edge kernel)
// [.., +1MB): dedup hash set (u32 keys, 0 = empty; zeroed in prep_w)
// [.., +64KB): WmuT bf16 [MM][FF]
// [.., +64KB): WsgT bf16 [MM][FF]
// [.., +2MB): zf bf16 fragment-interleaved: unit[(rt*16+kq)*16+l15] = 8 shorts
#define P_KL    0
#define P_EDGE  (64 * 16)
#define P_SP    (128 * 16)
#define Z_OFF   16384
#define Z_BYTES (NN * MM * 2)
#define HASH_OFF (Z_OFF + Z_BYTES)
#define WT_OFF  (HASH_OFF + HSLOTS * 4)
#define WT_BYTES (MM * FF * 2)
#define ZF_OFF  (WT_OFF + 2 * WT_BYTES)

__device__ __forceinline__ float wave_reduce(float v) {
    #pragma unroll
    for (int off = 32; off > 0; off >>= 1) v += __shfl_down(v, off);
    return v;
}
__device__ __forceinline__ unsigned short f2bf(float f) {
    unsigned int u = __float_as_uint(f);
    u += 0x7fffu + ((u >> 16) & 1u);   // round to nearest even
    return (unsigned short)(u >> 16);
}
__device__ __forceinline__ int4 pack8(float4 a, float4 b) {
    int4 p;
    p.x = (int)f2bf(a.x) | ((int)f2bf(a.y) << 16);
    p.y = (int)f2bf(a.z) | ((int)f2bf(a.w) << 16);
    p.z = (int)f2bf(b.x) | ((int)f2bf(b.y) << 16);
    p.w = (int)f2bf(b.z) | ((int)f2bf(b.w) << 16);
    return p;
}

// ---- prep: W transpose->bf16, zero partials, zero hash table -------------
__global__ __launch_bounds__(256)
void prep_w(const float* __restrict__ Wmu, const float* __restrict__ Wsg,
            unsigned short* __restrict__ WmuT, unsigned short* __restrict__ WsgT,
            float* __restrict__ part, unsigned int* __restrict__ ht) {
    const int t = blockIdx.x * 256 + threadIdx.x;   // 0..32767
    const int n = t >> 8, f = t & 255;
    WmuT[t] = f2bf(Wmu[f * MM + n]);
    WsgT[t] = f2bf(Wsg[f * MM + n]);
    if (t < 4096) part[t] = 0.f;          // 16 KB of partial slots
    uint4 z4 = {0u, 0u, 0u, 0u};
    ((uint4*)ht)[t * 2]     = z4;
    ((uint4*)ht)[t * 2 + 1] = z4;
}

// ---- encoder: MFMA GEMMs, W-fragments direct from global, 1 barrier ------
#define XP_I4 33   // int4 pitch per x row (32 data + 1 pad)
#define XP_S  264

__global__ __launch_bounds__(256)
void encoder_mfma(const float* __restrict__ x, const float* __restrict__ eps,
                  const unsigned short* __restrict__ WmuT,
                  const unsigned short* __restrict__ WsgT,
                  const float* __restrict__ bmu, const float* __restrict__ bsg,
                  unsigned short* __restrict__ zb, float* __restrict__ part) {
    __shared__ int4 ax[16 * XP_I4];   // 8.4 KB: 16 x-rows, K=256 bf16
    __shared__ float red[4];
    const int tid = threadIdx.x;
    const int wid = tid >> 6, lane = tid & 63;
    const int l15 = lane & 15, quad = lane >> 4;
    const int row0 = blockIdx.x * 16;

    {   // stage 16 rows x 256 cols of x as bf16
        const int r = tid >> 4, ch = tid & 15;
        const float4* g0 = (const float4*)(x + (size_t)(row0 + r) * FF + ch * 8);
        const float4* g1 = (const float4*)(x + (size_t)(row0 + r) * FF + (ch + 16) * 8);
        ax[r * XP_I4 + ch]      = pack8(g0[0], g0[1]);
        ax[r * XP_I4 + ch + 16] = pack8(g1[0], g1[1]);
    }
    __syncthreads();

    const short* sax = (const short*)ax;
    const int4* wtm = (const int4*)WmuT;   // row n = 32 int4 (K=256)
    const int4* wts = (const int4*)WsgT;

    f32x4 zero4 = {0.f, 0.f, 0.f, 0.f};
    f32x4 accm[2], accl[2];
    accm[0] = accm[1] = accl[0] = accl[1] = zero4;

    #pragma unroll
    for (int ks = 0; ks < 8; ++ks) {       // K = 8 x 32
        const bf16x8 a = *(const bf16x8*)&sax[l15 * XP_S + ks * 32 + quad * 8];
        #pragma unroll
        for (int j = 0; j < 2; ++j) {
            const int n = wid * 32 + j * 16 + l15;
            const bf16x8 bmf = *(const bf16x8*)&wtm[n * 32 + ks * 4 + quad];
            const bf16x8 bsf = *(const bf16x8*)&wts[n * 32 + ks * 4 + quad];
            accm[j] = __builtin_amdgcn_mfma_f32_16x16x32_bf16(a, bmf, accm[j], 0, 0, 0);
            accl[j] = __builtin_amdgcn_mfma_f32_16x16x32_bf16(a, bsf, accl[j], 0, 0, 0);
        }
    }

    // epilogue: C map col=lane&15, row=quad*4+reg [m89]
    float klp = 0.f;
    #pragma unroll
    for (int j = 0; j < 2; ++j) {
        const int col = wid * 32 + j * 16 + l15;
        const float bm = bmu[col], bs = bsg[col];
        #pragma unroll
        for (int r = 0; r < 4; ++r) {
            const int row = row0 + quad * 4 + r;
            const float mu = accm[j][r] + bm;
            const float ls = accl[j][r] + bs;
            const float sg = __expf(ls);
            const float zz = fmaf(sg, eps[(size_t)row * MM + col], mu);
            zb[(size_t)row * MM + col] = f2bf(zz);
            klp += 0.5f * (sg * sg + mu * mu - 1.f) - ls;
        }
    }

    klp = wave_reduce(klp);
    if (lane == 0) red[wid] = klp;
    __syncthreads();
    if (tid == 0)
        atomicAdd(&part[P_KL + (blockIdx.x & 63) * 16],
                  red[0] + red[1] + red[2] + red[3]);
}

// ---- zf relayout: zb row-major -> fragment-interleaved -------------------
// unit u = (rt*16 + kq)*16 + l15  holds zb[row=rt*16+l15][k=kq*8 .. +7]
__global__ __launch_bounds__(256)
void zf_shuffle(const unsigned short* __restrict__ zb,
                unsigned short* __restrict__ zf) {
    const int t = blockIdx.x * 256 + threadIdx.x;   // 0..131071 units
    const int rt = t >> 8, kq = (t >> 4) & 15, l15 = t & 15;
    const int4 v = *(const int4*)(zb + ((size_t)(rt * 16 + l15) * MM + kq * 8));
    ((int4*)zf)[t] = v;   // writes perfectly coalesced
}

// ---- edges: cooperative 16-lanes-per-edge, coalesced row reads -----------
__device__ __forceinline__ float dotpair(unsigned int a, unsigned int b) {
    const float al = __uint_as_float(a << 16);
    const float ah = __uint_as_float(a & 0xffff0000u);
    const float bl = __uint_as_float(b << 16);
    const float bh = __uint_as_float(b & 0xffff0000u);
    return fmaf(al, bl, ah * bh);
}

__global__ __launch_bounds__(256)
void edge_kernel(const int* __restrict__ ei, int E,
                 const unsigned short* __restrict__ zb,
                 unsigned int* __restrict__ ht, float* __restrict__ part) {
    const int tid = threadIdx.x;
    const int wid = tid >> 6, lane = tid & 63;
    const int g = lane >> 4, l15 = lane & 15;
    const int base0 = blockIdx.x * 128 + wid * 32;

    float accum = 0.f;
    #pragma unroll 2
    for (int p = 0; p < 8; ++p) {
        const int e = base0 + p * 4 + g;
        float s = 0.f;
        int i = 0, j = 0, a = 0, b = 0;
        if (e < E) {
            i = ei[e];
            j = ei[E + e];
            a = min(i, j); b = max(i, j);
            const uint4 ua = ((const uint4*)(zb + (size_t)a * MM))[l15];
            const uint4 ub = ((const uint4*)(zb + (size_t)b * MM))[l15];
            s = dotpair(ua.x, ub.x) + dotpair(ua.y, ub.y)
              + dotpair(ua.z, ub.z) + dotpair(ua.w, ub.w);
        }
        s += __shfl_down(s, 8);
        s += __shfl_down(s, 4);
        s += __shfl_down(s, 2);
        s += __shfl_down(s, 1);
        if (l15 == 0 && e < E && i != j) {
            const unsigned int key = (unsigned int)a * NN + b;
            unsigned int slot = (key * 2654435761u) & (HSLOTS - 1);
            bool first = false;
            for (;;) {
                const unsigned int old = atomicCAS(&ht[slot], 0u, key);
                if (old == 0u) { first = true; break; }
                if (old == key) break;
                slot = (slot + 1) & (HSLOTS - 1);
            }
            if (first) accum += s;
        }
    }
    accum = wave_reduce(accum);
    if (lane == 0)
        atomicAdd(&part[P_EDGE + ((blockIdx.x * 4 + wid) & 63) * 16], accum);
}

// ---- dominant: LDS-free MFMA z@z^T from fragment-interleaved zf ----------
// Every fragment load = 1KB contiguous per wave instruction. No LDS, no
// barriers. Two register banks give load/MFMA overlap with bounded VGPR.
__global__ __launch_bounds__(256)
void tile_kernel(const unsigned short* __restrict__ zf, float* __restrict__ part) {
    // decode linear q -> (bi, bj), bi<=bj
    const int q = blockIdx.x;
    int bi = (int)((129.0f - sqrtf(fmaxf(129.0f * 129.0f - 8.0f * (float)q, 0.f))) * 0.5f);
    bi = max(0, min(bi, 63));
    while ((bi + 1) * (129 - (bi + 1)) / 2 <= q && bi < 63) ++bi;
    while (bi * (129 - bi) / 2 > q) --bi;
    const int bj = bi + (q - bi * (129 - bi) / 2);

    const int tid = threadIdx.x;
    const int wid = tid >> 6, lane = tid & 63;
    const int wm = wid >> 1, wn = wid & 1;
    const int l15 = lane & 15, quad = lane >> 4;

    const bf16x8* zv = (const bf16x8*)zf;   // 16-B units
    // unit(rt, kq) for this lane = (rt*16 + kq)*16 + l15
    const int art = bi * 8 + wm * 4;        // A row-tiles art..art+3
    const int brt = bj * 8 + wn * 4;        // B row-tiles

    f32x4 zero4 = {0.f, 0.f, 0.f, 0.f};
    f32x4 acc[4][4];
    #pragma unroll
    for (int i = 0; i < 4; ++i)
        #pragma unroll
        for (int j = 0; j < 4; ++j) acc[i][j] = zero4;

    bf16x8 aA[4], bA[4], aB[4], bB[4];
    #define LOADF(dstA, dstB, ks)                                             \
        _Pragma("unroll")                                                     \
        for (int t = 0; t < 4; ++t) {                                         \
            dstA[t] = zv[((art + t) * 16 + (ks) * 4 + quad) * 16 + l15];      \
            dstB[t] = zv[((brt + t) * 16 + (ks) * 4 + quad) * 16 + l15];      \
        }
    #define MFMAS(srcA, srcB)                                                 \
        _Pragma("unroll")                                                     \
        for (int i = 0; i < 4; ++i)                                           \
            _Pragma("unroll")                                                 \
            for (int j = 0; j < 4; ++j)                                       \
                acc[i][j] = __builtin_amdgcn_mfma_f32_16x16x32_bf16(          \
                    srcA[i], srcB[j], acc[i][j], 0, 0, 0);

    LOADF(aA, bA, 0)
    LOADF(aB, bB, 1)
    MFMAS(aA, bA)
    LOADF(aA, bA, 2)
    MFMAS(aB, bB)
    LOADF(aB, bB, 3)
    MFMAS(aA, bA)
    MFMAS(aB, bB)
    #undef LOADF
    #undef MFMAS

    // softplus(v) ~= max(v,0) + e - e^2/2, e=exp(-|v|); err <= e^3/3
    float tsum = 0.f;
    if (bi != bj) {
        #pragma unroll
        for (int i = 0; i < 4; ++i)
            #pragma unroll
            for (int j = 0; j < 4; ++j)
                #pragma unroll
                for (int r = 0; r < 4; ++r) {
                    const float v = acc[i][j][r];
                    const float e = __expf(-fabsf(v));
                    tsum += fmaxf(v, 0.f) + e * fmaf(e, -0.5f, 1.f);
                }
    } else {
        const int rbase = wm * 64 + quad * 4;
        const int cbase = wn * 64 + l15;
        #pragma unroll
        for (int i = 0; i < 4; ++i)
            #pragma unroll
            for (int j = 0; j < 4; ++j)
                #pragma unroll
                for (int r = 0; r < 4; ++r)
                    if (cbase + j * 16 > rbase + i * 16 + r) {
                        const float v = acc[i][j][r];
                        const float e = __expf(-fabsf(v));
                        tsum += fmaxf(v, 0.f) + e * fmaf(e, -0.5f, 1.f);
                    }
    }

    tsum = wave_reduce(tsum);
    if (lane == 0)
        atomicAdd(&part[P_SP + ((q * 4 + wid) & 63) * 16], tsum);
}

// ---- final combine: sum 3 x 64 partial slots ----------------------------
__global__ void combine_kernel(const float* __restrict__ part,
                               float* __restrict__ out) {
    const int t = threadIdx.x;   // 64 threads
    float v = part[P_SP + t * 16] - part[P_EDGE + t * 16]
            + 0.001f * part[P_KL + t * 16];
    v = wave_reduce(v);
    if (t == 0) out[0] = v;
}

extern "C" void kernel_launch(void* const* d_in, const int* in_sizes, int n_in,
                              void* d_out, int out_size, void* d_ws, size_t ws_size,
                              hipStream_t stream) {
    const float* x   = (const float*)d_in[0];
    const int* ei    = (const int*)d_in[1];     // int32 on device
    const float* eps = (const float*)d_in[2];
    const float* Wmu = (const float*)d_in[3];
    const float* bmu = (const float*)d_in[4];
    const float* Wsg = (const float*)d_in[5];
    const float* bsg = (const float*)d_in[6];
    float* out = (float*)d_out;
    char* ws = (char*)d_ws;

    float* part = (float*)ws;
    unsigned short* zb = (unsigned short*)(ws + Z_OFF);
    unsigned int* ht = (unsigned int*)(ws + HASH_OFF);
    unsigned short* WmuT = (unsigned short*)(ws + WT_OFF);
    unsigned short* WsgT = (unsigned short*)(ws + WT_OFF + WT_BYTES);
    unsigned short* zf = (unsigned short*)(ws + ZF_OFF);
    const int E = in_sizes[1] / 2;

    prep_w<<<128, 256, 0, stream>>>(Wmu, Wsg, WmuT, WsgT, part, ht);
    encoder_mfma<<<NN / 16, 256, 0, stream>>>(x, eps, WmuT, WsgT, bmu, bsg, zb, part);
    zf_shuffle<<<512, 256, 0, stream>>>(zb, zf);
    edge_kernel<<<(E + 127) / 128, 256, 0, stream>>>(ei, E, zb, ht, part);
    tile_kernel<<<2080, 256, 0, stream>>>(zf, part);
    combine_kernel<<<1, 64, 0, stream>>>(part, out);
}

// Round 9
// 132.192 us; speedup vs baseline: 1.0182x; 1.0182x over previous
//
#include <hip/hip_runtime.h>

#define NN 8192
#define FF 256
#define MM 128
#define HSLOTS 262144   // power of 2, 2x edge count

typedef __attribute__((ext_vector_type(8))) short bf16x8;
typedef __attribute__((ext_vector_type(4))) float f32x4;

// ws layout (bytes):
// [0, 16K): partial sums, 3 arrays x 64 slots, 64B apart
// [16K, +2MB): zb bf16 [NN][MM]  (row-major, for edge path)
// [.., +1MB): dedup hash set (u32 keys, 0 = empty; zeroed in prep_w)
// [.., +64KB): WmuT bf16 [MM][FF]
// [.., +64KB): WsgT bf16 [MM][FF]
// [.., +2MB): zf bf16 fragment-interleaved: unit[(rt*16+kq)*16+l15] = 8 shorts
#define P_KL    0
#define P_EDGE  (64 * 16)
#define P_SP    (128 * 16)
#define Z_OFF   16384
#define Z_BYTES (NN * MM * 2)
#define HASH_OFF (Z_OFF + Z_BYTES)
#define WT_OFF  (HASH_OFF + HSLOTS * 4)
#define WT_BYTES (MM * FF * 2)
#define ZF_OFF  (WT_OFF + 2 * WT_BYTES)

__device__ __forceinline__ float wave_reduce(float v) {
    #pragma unroll
    for (int off = 32; off > 0; off >>= 1) v += __shfl_down(v, off);
    return v;
}
__device__ __forceinline__ unsigned short f2bf(float f) {
    unsigned int u = __float_as_uint(f);
    u += 0x7fffu + ((u >> 16) & 1u);   // round to nearest even
    return (unsigned short)(u >> 16);
}
__device__ __forceinline__ int4 pack8(float4 a, float4 b) {
    int4 p;
    p.x = (int)f2bf(a.x) | ((int)f2bf(a.y) << 16);
    p.y = (int)f2bf(a.z) | ((int)f2bf(a.w) << 16);
    p.z = (int)f2bf(b.x) | ((int)f2bf(b.y) << 16);
    p.w = (int)f2bf(b.z) | ((int)f2bf(b.w) << 16);
    return p;
}

// ---- prep: W transpose->bf16, zero partials, zero hash table -------------
__global__ __launch_bounds__(256)
void prep_w(const float* __restrict__ Wmu, const float* __restrict__ Wsg,
            unsigned short* __restrict__ WmuT, unsigned short* __restrict__ WsgT,
            float* __restrict__ part, unsigned int* __restrict__ ht) {
    const int t = blockIdx.x * 256 + threadIdx.x;   // 0..32767
    const int n = t >> 8, f = t & 255;
    WmuT[t] = f2bf(Wmu[f * MM + n]);
    WsgT[t] = f2bf(Wsg[f * MM + n]);
    if (t < 4096) part[t] = 0.f;          // 16 KB of partial slots
    uint4 z4 = {0u, 0u, 0u, 0u};
    ((uint4*)ht)[t * 2]     = z4;
    ((uint4*)ht)[t * 2 + 1] = z4;
}

// ---- encoder: MFMA GEMMs, dual-writes zb (row-major) + zf (fragment) -----
#define XP_I4 33   // int4 pitch per x row (32 data + 1 pad)
#define XP_S  264

__global__ __launch_bounds__(256)
void encoder_mfma(const float* __restrict__ x, const float* __restrict__ eps,
                  const unsigned short* __restrict__ WmuT,
                  const unsigned short* __restrict__ WsgT,
                  const float* __restrict__ bmu, const float* __restrict__ bsg,
                  unsigned short* __restrict__ zb, unsigned short* __restrict__ zf,
                  float* __restrict__ part) {
    __shared__ int4 ax[16 * XP_I4];   // 8.4 KB: 16 x-rows, K=256 bf16
    __shared__ float red[4];
    const int tid = threadIdx.x;
    const int wid = tid >> 6, lane = tid & 63;
    const int l15 = lane & 15, quad = lane >> 4;
    const int row0 = blockIdx.x * 16;

    {   // stage 16 rows x 256 cols of x as bf16
        const int r = tid >> 4, ch = tid & 15;
        const float4* g0 = (const float4*)(x + (size_t)(row0 + r) * FF + ch * 8);
        const float4* g1 = (const float4*)(x + (size_t)(row0 + r) * FF + (ch + 16) * 8);
        ax[r * XP_I4 + ch]      = pack8(g0[0], g0[1]);
        ax[r * XP_I4 + ch + 16] = pack8(g1[0], g1[1]);
    }
    __syncthreads();

    const short* sax = (const short*)ax;
    const int4* wtm = (const int4*)WmuT;   // row n = 32 int4 (K=256)
    const int4* wts = (const int4*)WsgT;

    f32x4 zero4 = {0.f, 0.f, 0.f, 0.f};
    f32x4 accm[2], accl[2];
    accm[0] = accm[1] = accl[0] = accl[1] = zero4;

    #pragma unroll
    for (int ks = 0; ks < 8; ++ks) {       // K = 8 x 32
        const bf16x8 a = *(const bf16x8*)&sax[l15 * XP_S + ks * 32 + quad * 8];
        #pragma unroll
        for (int j = 0; j < 2; ++j) {
            const int n = wid * 32 + j * 16 + l15;
            const bf16x8 bmf = *(const bf16x8*)&wtm[n * 32 + ks * 4 + quad];
            const bf16x8 bsf = *(const bf16x8*)&wts[n * 32 + ks * 4 + quad];
            accm[j] = __builtin_amdgcn_mfma_f32_16x16x32_bf16(a, bmf, accm[j], 0, 0, 0);
            accl[j] = __builtin_amdgcn_mfma_f32_16x16x32_bf16(a, bsf, accl[j], 0, 0, 0);
        }
    }

    // epilogue: C map col=lane&15, row=quad*4+reg [m89]
    const int rt = row0 >> 4;
    float klp = 0.f;
    #pragma unroll
    for (int j = 0; j < 2; ++j) {
        const int col = wid * 32 + j * 16 + l15;
        const float bm = bmu[col], bs = bsg[col];
        const int kq = col >> 3, c7 = col & 7;
        #pragma unroll
        for (int r = 0; r < 4; ++r) {
            const int row = row0 + quad * 4 + r;
            const float mu = accm[j][r] + bm;
            const float ls = accl[j][r] + bs;
            const float sg = __expf(ls);
            const float zz = fmaf(sg, eps[(size_t)row * MM + col], mu);
            const unsigned short zv = f2bf(zz);
            zb[(size_t)row * MM + col] = zv;
            // zf unit = (rt*16+kq)*16 + row%16 ; 8 lanes fill one 16B unit
            zf[(size_t)(((rt * 16 + kq) * 16) + quad * 4 + r) * 8 + c7] = zv;
            klp += 0.5f * (sg * sg + mu * mu - 1.f) - ls;
        }
    }

    klp = wave_reduce(klp);
    if (lane == 0) red[wid] = klp;
    __syncthreads();
    if (tid == 0)
        atomicAdd(&part[P_KL + (blockIdx.x & 63) * 16],
                  red[0] + red[1] + red[2] + red[3]);
}

// ---- helpers for fused kernel --------------------------------------------
__device__ __forceinline__ float dotpair(unsigned int a, unsigned int b) {
    const float al = __uint_as_float(a << 16);
    const float ah = __uint_as_float(a & 0xffff0000u);
    const float bl = __uint_as_float(b << 16);
    const float bh = __uint_as_float(b & 0xffff0000u);
    return fmaf(al, bl, ah * bh);
}

// ---- fused: edge blocks (latency-bound) + tile blocks (MFMA-bound) -------
// Edge blocks first so their loads launch early; tile blocks co-resident
// soak the idle MFMA/VALU pipes (m114 co-scheduling).
__global__ __launch_bounds__(256)
void fused_kernel(const int* __restrict__ ei, int E, int eblocks,
                  const unsigned short* __restrict__ zb,
                  const unsigned short* __restrict__ zf,
                  unsigned int* __restrict__ ht, float* __restrict__ part) {
    const int tid = threadIdx.x;
    const int wid = tid >> 6, lane = tid & 63;
    const int l15 = lane & 15, quad = lane >> 4;

    if ((int)blockIdx.x < eblocks) {
        // ================= edge path: 128 edges per block =================
        const int g = lane >> 4;
        const int base0 = blockIdx.x * 128 + wid * 32;
        float accum = 0.f;
        #pragma unroll 2
        for (int p = 0; p < 8; ++p) {
            const int e = base0 + p * 4 + g;
            float s = 0.f;
            int i = 0, j = 0, a = 0, b = 0;
            if (e < E) {
                i = ei[e];
                j = ei[E + e];
                a = min(i, j); b = max(i, j);
                const uint4 ua = ((const uint4*)(zb + (size_t)a * MM))[l15];
                const uint4 ub = ((const uint4*)(zb + (size_t)b * MM))[l15];
                s = dotpair(ua.x, ub.x) + dotpair(ua.y, ub.y)
                  + dotpair(ua.z, ub.z) + dotpair(ua.w, ub.w);
            }
            s += __shfl_down(s, 8);
            s += __shfl_down(s, 4);
            s += __shfl_down(s, 2);
            s += __shfl_down(s, 1);
            if (l15 == 0 && e < E && i != j) {
                const unsigned int key = (unsigned int)a * NN + b;
                unsigned int slot = (key * 2654435761u) & (HSLOTS - 1);
                bool first = false;
                for (;;) {
                    const unsigned int old = atomicCAS(&ht[slot], 0u, key);
                    if (old == 0u) { first = true; break; }
                    if (old == key) break;
                    slot = (slot + 1) & (HSLOTS - 1);
                }
                if (first) accum += s;
            }
        }
        accum = wave_reduce(accum);
        if (lane == 0)
            atomicAdd(&part[P_EDGE + ((blockIdx.x * 4 + wid) & 63) * 16], accum);
        return;
    }

    // ================= tile path: upper-tri 128x128 z@z^T ================
    const int q = blockIdx.x - eblocks;
    int bi = (int)((129.0f - sqrtf(fmaxf(129.0f * 129.0f - 8.0f * (float)q, 0.f))) * 0.5f);
    bi = max(0, min(bi, 63));
    while ((bi + 1) * (129 - (bi + 1)) / 2 <= q && bi < 63) ++bi;
    while (bi * (129 - bi) / 2 > q) --bi;
    const int bj = bi + (q - bi * (129 - bi) / 2);

    const int wm = wid >> 1, wn = wid & 1;
    const bf16x8* zv = (const bf16x8*)zf;   // 16-B units
    const int art = bi * 8 + wm * 4;        // A row-tiles art..art+3
    const int brt = bj * 8 + wn * 4;        // B row-tiles

    f32x4 zero4 = {0.f, 0.f, 0.f, 0.f};
    f32x4 acc[4][4];
    #pragma unroll
    for (int i = 0; i < 4; ++i)
        #pragma unroll
        for (int j = 0; j < 4; ++j) acc[i][j] = zero4;

    bf16x8 aA[4], bA[4], aB[4], bB[4];
    #define LOADF(dstA, dstB, ks)                                             \
        _Pragma("unroll")                                                     \
        for (int t = 0; t < 4; ++t) {                                         \
            dstA[t] = zv[((art + t) * 16 + (ks) * 4 + quad) * 16 + l15];      \
            dstB[t] = zv[((brt + t) * 16 + (ks) * 4 + quad) * 16 + l15];      \
        }
    #define MFMAS(srcA, srcB)                                                 \
        _Pragma("unroll")                                                     \
        for (int i = 0; i < 4; ++i)                                           \
            _Pragma("unroll")                                                 \
            for (int j = 0; j < 4; ++j)                                       \
                acc[i][j] = __builtin_amdgcn_mfma_f32_16x16x32_bf16(          \
                    srcA[i], srcB[j], acc[i][j], 0, 0, 0);

    LOADF(aA, bA, 0)
    LOADF(aB, bB, 1)
    MFMAS(aA, bA)
    LOADF(aA, bA, 2)
    MFMAS(aB, bB)
    LOADF(aB, bB, 3)
    MFMAS(aA, bA)
    MFMAS(aB, bB)
    #undef LOADF
    #undef MFMAS

    // softplus(v) ~= max(v,0) + e - e^2/2, e=exp(-|v|); err <= e^3/3
    float tsum = 0.f;
    if (bi != bj) {
        #pragma unroll
        for (int i = 0; i < 4; ++i)
            #pragma unroll
            for (int j = 0; j < 4; ++j)
                #pragma unroll
                for (int r = 0; r < 4; ++r) {
                    const float v = acc[i][j][r];
                    const float e = __expf(-fabsf(v));
                    tsum += fmaxf(v, 0.f) + e * fmaf(e, -0.5f, 1.f);
                }
    } else {
        const int rbase = wm * 64 + quad * 4;
        const int cbase = wn * 64 + l15;
        #pragma unroll
        for (int i = 0; i < 4; ++i)
            #pragma unroll
            for (int j = 0; j < 4; ++j)
                #pragma unroll
                for (int r = 0; r < 4; ++r)
                    if (cbase + j * 16 > rbase + i * 16 + r) {
                        const float v = acc[i][j][r];
                        const float e = __expf(-fabsf(v));
                        tsum += fmaxf(v, 0.f) + e * fmaf(e, -0.5f, 1.f);
                    }
    }

    tsum = wave_reduce(tsum);
    if (lane == 0)
        atomicAdd(&part[P_SP + ((q * 4 + wid) & 63) * 16], tsum);
}

// ---- final combine: sum 3 x 64 partial slots ----------------------------
__global__ void combine_kernel(const float* __restrict__ part,
                               float* __restrict__ out) {
    const int t = threadIdx.x;   // 64 threads
    float v = part[P_SP + t * 16] - part[P_EDGE + t * 16]
            + 0.001f * part[P_KL + t * 16];
    v = wave_reduce(v);
    if (t == 0) out[0] = v;
}

extern "C" void kernel_launch(void* const* d_in, const int* in_sizes, int n_in,
                              void* d_out, int out_size, void* d_ws, size_t ws_size,
                              hipStream_t stream) {
    const float* x   = (const float*)d_in[0];
    const int* ei    = (const int*)d_in[1];     // int32 on device
    const float* eps = (const float*)d_in[2];
    const float* Wmu = (const float*)d_in[3];
    const float* bmu = (const float*)d_in[4];
    const float* Wsg = (const float*)d_in[5];
    const float* bsg = (const float*)d_in[6];
    float* out = (float*)d_out;
    char* ws = (char*)d_ws;

    float* part = (float*)ws;
    unsigned short* zb = (unsigned short*)(ws + Z_OFF);
    unsigned int* ht = (unsigned int*)(ws + HASH_OFF);
    unsigned short* WmuT = (unsigned short*)(ws + WT_OFF);
    unsigned short* WsgT = (unsigned short*)(ws + WT_OFF + WT_BYTES);
    unsigned short* zf = (unsigned short*)(ws + ZF_OFF);
    const int E = in_sizes[1] / 2;
    const int eblocks = (E + 127) / 128;

    prep_w<<<128, 256, 0, stream>>>(Wmu, Wsg, WmuT, WsgT, part, ht);
    encoder_mfma<<<NN / 16, 256, 0, stream>>>(x, eps, WmuT, WsgT, bmu, bsg,
                                              zb, zf, part);
    fused_kernel<<<eblocks + 2080, 256, 0, stream>>>(ei, E, eblocks, zb, zf,
                                                     ht, part);
    combine_kernel<<<1, 64, 0, stream>>>(part, out);
}